// Round 4
// baseline (217.570 us; speedup 1.0000x reference)
//
#include <hip/hip_runtime.h>
#include <hip/hip_bf16.h>

// Shapes (fixed by the reference)
#define L_DIM 4
#define N_DIM 2048
#define DIN   1024
#define H_DIM 8
#define DH    64
#define INNER 512   // H*DH

typedef __attribute__((ext_vector_type(8))) short short8;
typedef __attribute__((ext_vector_type(4))) float f32x4;
typedef __attribute__((ext_vector_type(16))) float f32x16;

__device__ __forceinline__ unsigned short f2bf(float f) {
  unsigned u = __builtin_bit_cast(unsigned, f);
  u += 0x7fffu + ((u >> 16) & 1u);   // RNE
  return (unsigned short)(u >> 16);
}

// single-instruction 2xf32 -> packed bf16x2 (RNE); low16 = a, high16 = b
__device__ __forceinline__ unsigned cvtpk(float a, float b) {
  unsigned r;
  asm("v_cvt_pk_bf16_f32 %0, %1, %2" : "=v"(r) : "v"(a), "v"(b));
  return r;
}

// v_exp_f32 computes 2^x; log2e pre-folded into the softmax scale.
__device__ __forceinline__ float fexp2(float x) {
  float r;
  asm("v_exp_f32 %0, %1" : "=v"(r) : "v"(x));
  return r;
}

// async global->LDS, 16B per lane; lds base must be wave-uniform
typedef __attribute__((address_space(3))) unsigned int lds_uint;
typedef const __attribute__((address_space(1))) unsigned int glob_uint;
__device__ __forceinline__ void gl_lds16(const unsigned short* g,
                                         unsigned short* l) {
  __builtin_amdgcn_global_load_lds((glob_uint*)g, (lds_uint*)l, 16, 0, 0);
}

// ------------------------------------------------- fused casts + mask bias
__global__ void cast_all(const float* __restrict__ x,
                         const float* __restrict__ wq,
                         const float* __restrict__ wk,
                         const float* __restrict__ wv,
                         const float* __restrict__ wo,
                         unsigned short* __restrict__ xb,
                         unsigned short* __restrict__ w3,
                         unsigned short* __restrict__ wob,
                         const unsigned char* __restrict__ mraw,
                         float* __restrict__ bias) {
  __shared__ int votes[2];
  int bid = blockIdx.x, t = threadIdx.x;
  if (bid == 10240) {
    // mask -> additive bias (0 valid, -1e30 masked); dtype sniffed.
    if (t < 2) votes[t] = 0;
    __syncthreads();
    const unsigned int* m32 = (const unsigned int*)mraw;
    int anyf = 0, any8 = 0;
    for (int i = t; i < 2048; i += 256) {
      unsigned w = m32[i];
      if (w == 0x3f800000u) anyf = 1;
      if (w & 0xffffff00u) any8 = 1;
    }
    if (anyf) atomicOr(&votes[0], 1);
    if (any8) atomicOr(&votes[1], 1);
    __syncthreads();
    int fmt = votes[0] ? 2 : (votes[1] ? 1 : 0);
    for (int i = t; i < L_DIM * N_DIM; i += 256) {
      int mv;
      if (fmt == 2)      mv = ((const float*)mraw)[i] != 0.0f;
      else if (fmt == 1) mv = mraw[i] != 0;
      else               mv = ((const int*)mraw)[i] != 0;
      bias[i] = mv ? 0.0f : -1e30f;
    }
    return;
  }
  int i = (bid * 256 + t) * 4;
  const float* src; unsigned short* dst; int off;
  if (i < 8388608)      { src = x;  dst = xb;           off = i; }
  else if (i < 8912896) { src = wq; dst = w3;           off = i - 8388608; }
  else if (i < 9437184) { src = wk; dst = w3 + 524288;  off = i - 8912896; }
  else if (i < 9961472) { src = wv; dst = w3 + 1048576; off = i - 9437184; }
  else                  { src = wo; dst = wob;          off = i - 9961472; }
  float4 f = *(const float4*)(src + off);
  ushort4 o4;
  o4.x = f2bf(f.x); o4.y = f2bf(f.y); o4.z = f2bf(f.z); o4.w = f2bf(f.w);
  *(ushort4*)(dst + off) = o4;
}

// ---------------------------------------------------------------- QKV GEMM
// C[8192][1536] = Xb[8192][1024] @ W3^T. Double-buffered LDS, one barrier
// per K-step (r8; neutral vs m97 2-barrier but keeps the DMA in flight).
// Epilogue: Q,K head-major [lh][n][64]; V blocks (blockIdx.y>=8) transpose
// through LDS (reusing the staging buffer), store vT coalesced b128.
__launch_bounds__(256, 3)
__global__ void gemm_qkv(const unsigned short* __restrict__ xb,
                         const unsigned short* __restrict__ w3,
                         unsigned short* __restrict__ qp,
                         unsigned short* __restrict__ kp,
                         unsigned short* __restrict__ vtp) {
  __shared__ __align__(16) unsigned short Sh[16384];  // A dbuf | B dbuf
  const int tid = threadIdx.x, lane = tid & 63, wid = tid >> 6;
  const int l16 = lane & 15, quad = lane >> 4;
  const int wm = wid >> 1, wn = wid & 1;
  const int m0 = blockIdx.x * 128, n0 = blockIdx.y * 128;

  int aoff[2], boff[2], lofs[2];
#pragma unroll
  for (int it = 0; it < 2; ++it) {
    int c = it * 256 + wid * 64 + lane;
    int row = c >> 2, kseg = c & 3;
    aoff[it] = (m0 + row) * DIN + kseg * 8;
    boff[it] = (n0 + row) * DIN + kseg * 8;
    lofs[it] = (it * 256 + wid * 64) * 8;
  }

#pragma unroll
  for (int it = 0; it < 2; ++it) {
    gl_lds16(&xb[aoff[it]], &Sh[lofs[it]]);
    gl_lds16(&w3[boff[it]], &Sh[8192 + lofs[it]]);
  }

  f32x4 acc[4][4] = {};
  for (int t = 0; t < 32; ++t) {
    const int buf = t & 1;
    __syncthreads();
    if (t < 31) {
      int kt2 = (t + 1) * 32, b2 = buf ^ 1;
#pragma unroll
      for (int it = 0; it < 2; ++it) {
        gl_lds16(&xb[aoff[it] + kt2], &Sh[b2 * 4096 + lofs[it]]);
        gl_lds16(&w3[boff[it] + kt2], &Sh[8192 + b2 * 4096 + lofs[it]]);
      }
    }
    const unsigned short* As = &Sh[buf * 4096];
    const unsigned short* Bs = &Sh[8192 + buf * 4096];
    short8 af[4], bf[4];
#pragma unroll
    for (int mt = 0; mt < 4; ++mt)
      af[mt] = *(const short8*)&As[(wm * 64 + mt * 16 + l16) * 32 + quad * 8];
#pragma unroll
    for (int nt = 0; nt < 4; ++nt)
      bf[nt] = *(const short8*)&Bs[(wn * 64 + nt * 16 + l16) * 32 + quad * 8];
#pragma unroll
    for (int mt = 0; mt < 4; ++mt)
#pragma unroll
      for (int nt = 0; nt < 4; ++nt)
        acc[mt][nt] = __builtin_amdgcn_mfma_f32_16x16x32_bf16(
            af[mt], bf[nt], acc[mt][nt], 0, 0, 0);
  }
  if (blockIdx.y >= 8) {
    // whole 128x128 tile is V: transpose via LDS, store coalesced to vT
    const int l = m0 >> 11, mloc = m0 & 2047;
#pragma unroll
    for (int chunk = 0; chunk < 2; ++chunk) {
      __syncthreads();
      if (wn == chunk) {
#pragma unroll
        for (int mt = 0; mt < 4; ++mt)
#pragma unroll
          for (int nt = 0; nt < 4; ++nt) {
            int col = nt * 16 + l16;              // 0..63 within chunk
            int rowb = wm * 64 + mt * 16 + quad * 4;
            ushort4 pv;
            pv.x = f2bf(acc[mt][nt][0]);
            pv.y = f2bf(acc[mt][nt][1]);
            pv.z = f2bf(acc[mt][nt][2]);
            pv.w = f2bf(acc[mt][nt][3]);
            *(ushort4*)&Sh[col * 136 + rowb] = pv;
          }
      }
      __syncthreads();
      int hh = ((n0 + chunk * 64) & 511) >> 6;
#pragma unroll
      for (int it = 0; it < 4; ++it) {
        int c = it * 256 + tid;
        int cl = c >> 4, seg = c & 15;  // d = cl, n-seg
        short8 vv = *(const short8*)&Sh[cl * 136 + seg * 8];
        *(short8*)&vtp[((size_t)((l * H_DIM + hh) * DH + cl)) * N_DIM + mloc +
                       seg * 8] = vv;
      }
    }
  } else {
#pragma unroll
    for (int mt = 0; mt < 4; ++mt)
#pragma unroll
      for (int nt = 0; nt < 4; ++nt)
#pragma unroll
        for (int r = 0; r < 4; ++r) {
          int grow = m0 + wm * 64 + mt * 16 + quad * 4 + r;
          int gcol = n0 + wn * 64 + nt * 16 + l16;
          unsigned short bv = f2bf(acc[mt][nt][r]);
          int h = (gcol & 511) >> 6, d = gcol & 63;
          int l = grow >> 11, n = grow & 2047;
          unsigned short* dst = (gcol >> 9) ? kp : qp;
          dst[(((l * H_DIM + h) * N_DIM + n) * DH) + d] = bv;
        }
  }
}

// ---------------------------------------------------------------- attention
// r9 (resubmit after infra failure): 32x32x16 MFMA path, Pw ELIMINATED.
// Swapped QK^T (S^T = mfma(K, Q)) puts qrow = lane&31, so each lane owns
// the full P-slice for its output row. The C-layout key split
// ({0-3,8-11}+4hi) is reconciled with PV's A-operand (keys hi*8+e) by
// permuting the PV contraction dim on BOTH operands:
// pi(hi,e) = 4hi + (e&3) + 8*(e>>2). P packs lane-locally (16 cvt_pk, no
// cross-lane exchange); V's B-frag becomes two 8B LDS reads. Per tile vs
// r8: 8 ds_writes + Pw lgkm roundtrip deleted, 32->16 MFMAs (same FLOPs,
// -13% issue cycles), LDS 40->32 KB. setprio(1) around MFMA clusters
// (independent blocks per CU -> m191 regime). XCD swizzle keeps K/V
// L2-resident; granule-rotation swizzles keep LDS near conflict-min.
__launch_bounds__(128, 2)
__global__ void attn_kernel(const unsigned short* __restrict__ qg,
                            const unsigned short* __restrict__ kg,
                            const unsigned short* __restrict__ vtg,
                            const float* __restrict__ bias,
                            unsigned short* __restrict__ aout) {
  __shared__ __align__(16) unsigned short Ks[2][64 * 64];   // 2x8 KB
  __shared__ __align__(16) unsigned short Vs[2][64 * 64];   // 2x8 KB
  const int tid = threadIdx.x, lane = tid & 63, wid = tid >> 6;  // wid 0..1
  const int l32 = lane & 31, hi = lane >> 5;
  // XCD swizzle: bid%8 = XCD (round-robin dispatch); 4 lh per XCD.
  const int bid = blockIdx.x;
  const int xcd = bid & 7, j = bid >> 3;      // j in 0..127
  const int lh = xcd * 4 + (j >> 5);          // 32 q-blocks per lh
  const int q0 = (j & 31) << 6;               // q-tiles of 64
  const int l = lh >> 3, h = lh & 7;
  const unsigned short* Qb = qg + (size_t)lh * N_DIM * DH;
  const unsigned short* Kb = kg + (size_t)lh * N_DIM * DH;
  const unsigned short* Vt = vtg + (size_t)lh * DH * N_DIM;
  const float* bl = bias + l * N_DIM;

  // Q B-frags for swapped QK^T: col = qrow = l32, k = hi*8+e (4 k-steps)
  short8 qf[4];
#pragma unroll
  for (int ks = 0; ks < 4; ++ks)
    qf[ks] = *(const short8*)&Qb[(q0 + wid * 32 + l32) * DH + ks * 16 +
                                 hi * 8];

  f32x16 o[2] = {};   // O C-layout: col=l32=d(+nt*32), row=(r&3)+8*(r>>2)+4hi
  float lsum = 0.f;   // per-lane partial row-sum for qrow = l32

  // staging offsets (loop-invariant): 64 rows x 8 slots of 16B, slot rotated
  // by row; K rows = keys (64 dh each), V rows = d (64 keys each).
  int kof[4], ldsb[4];
  size_t vof[4];
#pragma unroll
  for (int it = 0; it < 4; ++it) {
    int cb = it * 128 + wid * 64, c = cb + lane;
    int rr = c >> 3, sl = c & 7, gs = (sl + rr) & 7;
    kof[it] = rr * DH + gs * 8;
    vof[it] = (size_t)rr * N_DIM + gs * 8;
    ldsb[it] = cb * 8;
  }

  // stage tile 0 into buffer 0
#pragma unroll
  for (int it = 0; it < 4; ++it) {
    gl_lds16(&Kb[kof[it]], &Ks[0][ldsb[it]]);
    gl_lds16(&Vt[vof[it]], &Vs[0][ldsb[it]]);
  }

  for (int t = 0; t < 32; ++t) {
    const int kv = t << 6, buf = t & 1;
    __syncthreads();  // buf's DMA (issued last iter) landed; everyone done
                      // reading buf^1 from tile t-1
    if (t < 31) {     // issue tile t+1's DMA into the other buffer NOW
      int kv2 = kv + 64, b2 = buf ^ 1;
#pragma unroll
      for (int it = 0; it < 4; ++it) {
        gl_lds16(&Kb[(kv2 << 6) + kof[it]], &Ks[b2][ldsb[it]]);
        gl_lds16(&Vt[vof[it] + kv2], &Vs[b2][ldsb[it]]);
      }
    }
    const unsigned short* Kst = Ks[buf];
    const unsigned short* Vst = Vs[buf];

    // S^T = K·Q : per wave 2 m-tiles (keys) x 32 qrows, 4 k-steps of dh=16
    f32x16 sc[2] = {};
    __builtin_amdgcn_s_setprio(1);
#pragma unroll
    for (int ks = 0; ks < 4; ++ks) {
      int cg = ks * 2 + hi;  // wanted dh-granule
#pragma unroll
      for (int mt = 0; mt < 2; ++mt) {
        int key = mt * 32 + l32;
        short8 kf =
            *(const short8*)&Kst[key * 64 + ((cg - key) & 7) * 8];
        sc[mt] = __builtin_amdgcn_mfma_f32_32x32x16_bf16(kf, qf[ks], sc[mt],
                                                         0, 0, 0);
      }
    }
    __builtin_amdgcn_s_setprio(0);

    // softmax: lane holds P[qrow=l32][key = mt*32 + rg*8 + 4hi + j]
    unsigned pk[2][4][2];
#pragma unroll
    for (int mt = 0; mt < 2; ++mt)
#pragma unroll
      for (int rg = 0; rg < 4; ++rg) {
        float4 b4 = *(const float4*)&bl[kv + mt * 32 + rg * 8 + hi * 4];
        // exp(s*0.125 + b) == exp2(s*(0.125*log2e) + b'); b in {0,-1e30}
        float p0 = fexp2(fmaf(sc[mt][rg * 4 + 0], 0.18033688011f, b4.x));
        float p1 = fexp2(fmaf(sc[mt][rg * 4 + 1], 0.18033688011f, b4.y));
        float p2 = fexp2(fmaf(sc[mt][rg * 4 + 2], 0.18033688011f, b4.z));
        float p3 = fexp2(fmaf(sc[mt][rg * 4 + 3], 0.18033688011f, b4.w));
        lsum += (p0 + p1) + (p2 + p3);
        pk[mt][rg][0] = cvtpk(p0, p1);
        pk[mt][rg][1] = cvtpk(p2, p3);
      }

    // O += P·V with key-permuted contraction pi(hi,e)=4hi+(e&3)+8*(e>>2):
    // A k-slots are lane-local pk words; B k-slots are two 8B V reads.
    __builtin_amdgcn_s_setprio(1);
#pragma unroll
    for (int ks = 0; ks < 4; ++ks) {
      int mt = ks >> 1, s = ks & 1;
      short8 pa = __builtin_bit_cast(
          short8, make_uint4(pk[mt][s * 2][0], pk[mt][s * 2][1],
                             pk[mt][s * 2 + 1][0], pk[mt][s * 2 + 1][1]));
#pragma unroll
      for (int nt = 0; nt < 2; ++nt) {
        int d = nt * 32 + l32;
        const unsigned short* vr = &Vst[d * 64 + hi * 4];
        uint2 v0 = *(const uint2*)&vr[(((ks * 2) - d) & 7) * 8];
        uint2 v1 = *(const uint2*)&vr[(((ks * 2 + 1) - d) & 7) * 8];
        short8 vb =
            __builtin_bit_cast(short8, make_uint4(v0.x, v0.y, v1.x, v1.y));
        o[nt] = __builtin_amdgcn_mfma_f32_32x32x16_bf16(pa, vb, o[nt],
                                                        0, 0, 0);
      }
    }
    __builtin_amdgcn_s_setprio(0);
  }

  // full row-sum for qrow = l32 (keys split across hi halves)
  lsum += __shfl_xor(lsum, 32);
  float inv = 1.f / lsum;
  const int rbase = l * N_DIM + q0 + wid * 32;
#pragma unroll
  for (int rg = 0; rg < 4; ++rg)
#pragma unroll
    for (int jj = 0; jj < 4; ++jj) {
      int row = rg * 8 + hi * 4 + jj;          // qrow within 32
      float invr = __shfl(inv, row);
#pragma unroll
      for (int nt = 0; nt < 2; ++nt)
        aout[(size_t)(rbase + row) * INNER + h * DH + nt * 32 + l32] =
            f2bf(o[nt][rg * 4 + jj] * invr);
    }
}

// ---------------------------------------------------------------- out GEMM
// out[8192][1024] = attn[8192][512] @ Wo^T + bo (fp32 out), dbuf one-barrier.
__launch_bounds__(256, 3)
__global__ void gemm_out(const unsigned short* __restrict__ a,
                         const unsigned short* __restrict__ wo,
                         const float* __restrict__ bo,
                         float* __restrict__ out) {
  __shared__ __align__(16) unsigned short Sh[16384];  // A dbuf | B dbuf
  const int tid = threadIdx.x, lane = tid & 63, wid = tid >> 6;
  const int l16 = lane & 15, quad = lane >> 4;
  const int wm = wid >> 1, wn = wid & 1;
  const int m0 = blockIdx.x * 128, n0 = blockIdx.y * 128;

  int aoff[2], boff[2], lofs[2];
#pragma unroll
  for (int it = 0; it < 2; ++it) {
    int c = it * 256 + wid * 64 + lane;
    int row = c >> 2, kseg = c & 3;
    aoff[it] = (m0 + row) * INNER + kseg * 8;
    boff[it] = (n0 + row) * INNER + kseg * 8;
    lofs[it] = (it * 256 + wid * 64) * 8;
  }

#pragma unroll
  for (int it = 0; it < 2; ++it) {
    gl_lds16(&a[aoff[it]], &Sh[lofs[it]]);
    gl_lds16(&wo[boff[it]], &Sh[8192 + lofs[it]]);
  }

  f32x4 acc[4][4] = {};
  for (int t = 0; t < 16; ++t) {
    const int buf = t & 1;
    __syncthreads();
    if (t < 15) {
      int kt2 = (t + 1) * 32, b2 = buf ^ 1;
#pragma unroll
      for (int it = 0; it < 2; ++it) {
        gl_lds16(&a[aoff[it] + kt2], &Sh[b2 * 4096 + lofs[it]]);
        gl_lds16(&wo[boff[it] + kt2], &Sh[8192 + b2 * 4096 + lofs[it]]);
      }
    }
    const unsigned short* As = &Sh[buf * 4096];
    const unsigned short* Bs = &Sh[8192 + buf * 4096];
    short8 af[4], bf[4];
#pragma unroll
    for (int mt = 0; mt < 4; ++mt)
      af[mt] = *(const short8*)&As[(wm * 64 + mt * 16 + l16) * 32 + quad * 8];
#pragma unroll
    for (int nt = 0; nt < 4; ++nt)
      bf[nt] = *(const short8*)&Bs[(wn * 64 + nt * 16 + l16) * 32 + quad * 8];
#pragma unroll
    for (int mt = 0; mt < 4; ++mt)
#pragma unroll
      for (int nt = 0; nt < 4; ++nt)
        acc[mt][nt] = __builtin_amdgcn_mfma_f32_16x16x32_bf16(
            af[mt], bf[nt], acc[mt][nt], 0, 0, 0);
  }
#pragma unroll
  for (int mt = 0; mt < 4; ++mt)
#pragma unroll
    for (int nt = 0; nt < 4; ++nt)
#pragma unroll
      for (int r = 0; r < 4; ++r) {
        int grow = m0 + wm * 64 + mt * 16 + quad * 4 + r;
        int gcol = n0 + wn * 64 + nt * 16 + l16;
        out[(size_t)grow * DIN + gcol] = acc[mt][nt][r] + bo[gcol];
      }
}

// ---------------------------------------------------------------- launch
extern "C" void kernel_launch(void* const* d_in, const int* in_sizes, int n_in,
                              void* d_out, int out_size, void* d_ws,
                              size_t ws_size, hipStream_t stream) {
  const float* x  = (const float*)d_in[0];
  const float* Wq = (const float*)d_in[1];
  const float* Wk = (const float*)d_in[2];
  const float* Wv = (const float*)d_in[3];
  const float* Wo = (const float*)d_in[4];
  const float* bo = (const float*)d_in[5];
  const unsigned char* mask = (const unsigned char*)d_in[6];
  float* out = (float*)d_out;

  char* ws = (char*)d_ws;
  unsigned short* xb  = (unsigned short*)(ws + 0);         // 16 MB
  unsigned short* w3  = (unsigned short*)(ws + 16777216);  // 3 MB
  unsigned short* wob = (unsigned short*)(ws + 19922944);  // 1 MB
  unsigned short* q   = (unsigned short*)(ws + 20971520);  // 8 MB
  unsigned short* k   = (unsigned short*)(ws + 29360128);  // 8 MB
  unsigned short* vt  = (unsigned short*)(ws + 37748736);  // 8 MB (transposed)
  unsigned short* att = (unsigned short*)(ws + 46137344);  // 8 MB
  float* bias         = (float*)(ws + 54525952);           // 32 KB

  cast_all<<<10241, 256, 0, stream>>>(x, Wq, Wk, Wv, Wo, xb, w3, wob, mask,
                                      bias);
  gemm_qkv<<<dim3(64, 12), 256, 0, stream>>>(xb, w3, q, k, vt);
  attn_kernel<<<1024, 128, 0, stream>>>(q, k, vt, bias, att);
  gemm_out<<<dim3(64, 8), 256, 0, stream>>>(att, wob, bo, out);
}